// Round 5
// baseline (145.692 us; speedup 1.0000x reference)
//
#include <hip/hip_runtime.h>
#include <math.h>

#define HID 64
#define KB 9            // NUM_BINS - 1
#define NB 10
#define NTOT (128 * 20000)
#define EPT 4
#define BLOCK 256
#define LEAKY 0.01f
#define RSTRIDE 20      // floats per region row (9 A + 9 C + 2 pad)
#define TAB_FLOATS (128 + 65 * RSTRIDE)   // 128 padded thresholds + 65 regions = 1428
#define WS_BYTES (TAB_FLOATS * 4)
#define SENT 3.0e38f
#define SOSTRIDE 11     // float4s per thread in staging LDS (odd -> all 8 bank-quads)

typedef float v4f __attribute__((ext_vector_type(4)));

// ---------------- setup: 65 blocks x 64 threads, one region per wave ----------------
// ws[0..127]: sorted thresholds t_j = -b1_j/W1_j padded with +SENT;
// ws[128 + r*RSTRIDE + {k, KB+k}]: A[r][k], C[r][k] with logits_k(x) = A*x + C
// on region r = count(t <= x). Units iterate in ORIGINAL order (R2 bug: the
// sort must only affect the threshold array, never the (W1,b1,W2) pairing).
__global__ __launch_bounds__(64) void setup_kernel(
    const float* __restrict__ W1, const float* __restrict__ b1,
    const float* __restrict__ W2, const float* __restrict__ b2,
    float* __restrict__ ws)
{
    __shared__ float t_lds[HID], w_lds[HID], b_lds[HID], tsrt[HID];
    __shared__ float w2_lds[HID * KB];
    __shared__ float red[18 * 65];   // rows padded to 65 -> conflict-free reduce

    const int j = threadIdx.x;       // unit index (original order)
    const int r = blockIdx.x;        // region index 0..64
    const float w = W1[j], b = b1[j];
    const float t = (w != 0.0f) ? (-b / w) : -SENT;  // w==0: constant sign, park at -inf
    t_lds[j] = t; w_lds[j] = w; b_lds[j] = b;
    #pragma unroll
    for (int q = j; q < HID * KB; q += 64) w2_lds[q] = W2[q];
    __syncthreads();

    int rank = 0;                    // rank sort (unique ranks via index tiebreak)
    for (int i = 0; i < HID; ++i) {
        float ti = t_lds[i];
        rank += (ti < t || (ti == t && i < j)) ? 1 : 0;
    }
    tsrt[rank] = t;
    __syncthreads();

    float xm;   // point strictly inside region r
    if (r == 0)        xm = tsrt[0] - 1.0f;
    else if (r == HID) xm = tsrt[HID - 1] + 1.0f;
    else               xm = 0.5f * (tsrt[r - 1] + tsrt[r]);

    const float s = (fmaf(w, xm, b) >= 0.0f) ? 1.0f : LEAKY;
    #pragma unroll
    for (int k = 0; k < KB; ++k) {
        const float w2s = w2_lds[j * KB + k] * s;
        red[(2 * k) * 65 + j]     = w2s * w;   // A contribution
        red[(2 * k + 1) * 65 + j] = w2s * b;   // C contribution
    }
    __syncthreads();

    if (j < 18) {   // threads 0..17 each sum one row of 64 (deterministic order)
        float acc = 0.0f;
        for (int i = 0; i < HID; ++i) acc += red[j * 65 + i];
        const int k = j >> 1;
        if (j & 1) ws[128 + r * RSTRIDE + KB + k] = acc + b2[k];  // C
        else       ws[128 + r * RSTRIDE + k]      = acc;          // A
    }
    if (r == 0) { ws[j] = tsrt[j]; ws[64 + j] = SENT; }
}

// ---------------- main: table lookup + softmax, conflict-free LDS-staged stores ----------------
__global__ __launch_bounds__(BLOCK) void main_kernel(
    const float* __restrict__ expr, const float* __restrict__ ws,
    float* __restrict__ out)
{
    __shared__ float ts[128];
    __shared__ float tab[65 * RSTRIDE];
    __shared__ v4f so[BLOCK * SOSTRIDE];   // padded stride: write quad=(3*tid+q)&7, all 8 used

    const int tid = threadIdx.x;
    for (int t = tid; t < TAB_FLOATS; t += BLOCK) {
        float v = ws[t];
        if (t < 128) ts[t] = v; else tab[t - 128] = v;
    }
    __syncthreads();

    const int i0 = (blockIdx.x * BLOCK + tid) * EPT;
    const float4 xv = *(const float4*)(expr + i0);
    float x[EPT] = {xv.x, xv.y, xv.z, xv.w};
    float o[EPT * NB];
    float msk[EPT];
    #pragma unroll
    for (int e = 0; e < EPT; ++e) {
        const float xe = x[e];
        // region = count(sorted thresholds <= xe); padding keeps all 7 probes in-bounds
        int idx = 0;
        #pragma unroll
        for (int s = 64; s >= 1; s >>= 1)
            idx += (ts[idx + s - 1] <= xe) ? s : 0;
        const float* row = tab + idx * RSTRIDE;
        float lg[KB];
        #pragma unroll
        for (int k = 0; k < KB; ++k) lg[k] = fmaf(row[k], xe, row[KB + k]);
        float m = lg[0];
        #pragma unroll
        for (int k = 1; k < KB; ++k) m = fmaxf(m, lg[k]);
        float p[KB];
        float s = 0.0f;
        #pragma unroll
        for (int k = 0; k < KB; ++k) { p[k] = __expf(lg[k] - m); s += p[k]; }
        const float rcp = __frcp_rn(s);
        const bool nz = (xe != 0.0f);
        msk[e] = nz ? 1.0f : 0.0f;
        o[e * NB] = nz ? 0.0f : 1.0f;
        #pragma unroll
        for (int k = 0; k < KB; ++k) o[e * NB + 1 + k] = nz ? p[k] * rcp : 0.0f;
    }

    // mask output: lane-contiguous, nontemporal
    {
        v4f mv = {msk[0], msk[1], msk[2], msk[3]};
        __builtin_nontemporal_store(mv, (v4f*)(out + (size_t)NTOT * NB + i0));
    }

    // probs: stage thread's 10 float4s at padded stride 11 (conflict-free writes)
    #pragma unroll
    for (int q = 0; q < NB; ++q)
        so[tid * SOSTRIDE + q] = ((const v4f*)o)[q];
    __syncthreads();
    // linear re-read: global f4 index g = q*256+tid -> logical (t=g/10, r=g%10),
    // phys = t*11+r. Incremental: g += 256 == t += 25, r += 6 (one wrap max).
    float* gout = out + (size_t)blockIdx.x * (BLOCK * EPT * NB);
    int t = tid / 10;
    int r = tid - t * 10;
    #pragma unroll
    for (int q = 0; q < NB; ++q) {
        const int g = q * BLOCK + tid;
        v4f v = so[t * SOSTRIDE + r];
        __builtin_nontemporal_store(v, (v4f*)(gout + (size_t)g * 4));
        t += 25; r += 6;
        if (r >= 10) { r -= 10; t += 1; }
    }
}

// ---------------- fallback if d_ws too small: self-contained, per-block table ----------------
__global__ __launch_bounds__(BLOCK) void fused_kernel(
    const float* __restrict__ expr,
    const float* __restrict__ W1, const float* __restrict__ b1,
    const float* __restrict__ W2, const float* __restrict__ b2,
    float* __restrict__ out)
{
    __shared__ float ts[128];
    __shared__ float tab[65 * RSTRIDE];
    __shared__ float st[HID], sw[HID], sb[HID], tsrt[HID];
    const int tid = threadIdx.x;
    if (tid < HID) {
        float w = W1[tid], b = b1[tid];
        st[tid] = (w != 0.0f) ? (-b / w) : -SENT;
        sw[tid] = w; sb[tid] = b;
    }
    __syncthreads();
    if (tid < HID) {
        float t = st[tid];
        int r = 0;
        for (int i = 0; i < HID; ++i) {
            float ti = st[i];
            r += (ti < t || (ti == t && i < tid)) ? 1 : 0;
        }
        tsrt[r] = t;
    }
    __syncthreads();
    if (tid < 128) ts[tid] = (tid < HID) ? tsrt[tid] : SENT;
    for (int item = tid; item < 65 * KB; item += BLOCK) {
        int r = item / KB, k = item - r * KB;
        float xm;
        if (r == 0)        xm = tsrt[0] - 1.0f;
        else if (r == HID) xm = tsrt[HID - 1] + 1.0f;
        else               xm = 0.5f * (tsrt[r - 1] + tsrt[r]);
        float A = 0.0f, C = b2[k];
        for (int j = 0; j < HID; ++j) {
            float w = sw[j], bb = sb[j];
            float s = (fmaf(w, xm, bb) >= 0.0f) ? 1.0f : LEAKY;
            float w2s = W2[j * KB + k] * s;
            A = fmaf(w2s, w, A);
            C = fmaf(w2s, bb, C);
        }
        tab[r * RSTRIDE + k] = A;
        tab[r * RSTRIDE + KB + k] = C;
    }
    __syncthreads();
    const int i0 = (blockIdx.x * BLOCK + tid) * EPT;
    const float4 xv = *(const float4*)(expr + i0);
    float x[EPT] = {xv.x, xv.y, xv.z, xv.w};
    float o[EPT * NB]; float msk[EPT];
    #pragma unroll
    for (int e = 0; e < EPT; ++e) {
        const float xe = x[e];
        int idx = 0;
        #pragma unroll
        for (int s = 64; s >= 1; s >>= 1) idx += (ts[idx + s - 1] <= xe) ? s : 0;
        const float* row = tab + idx * RSTRIDE;
        float lg[KB];
        #pragma unroll
        for (int k = 0; k < KB; ++k) lg[k] = fmaf(row[k], xe, row[KB + k]);
        float m = lg[0];
        #pragma unroll
        for (int k = 1; k < KB; ++k) m = fmaxf(m, lg[k]);
        float p[KB]; float s = 0.0f;
        #pragma unroll
        for (int k = 0; k < KB; ++k) { p[k] = __expf(lg[k] - m); s += p[k]; }
        const float rcp = __frcp_rn(s);
        const bool nz = (xe != 0.0f);
        msk[e] = nz ? 1.0f : 0.0f;
        o[e * NB] = nz ? 0.0f : 1.0f;
        #pragma unroll
        for (int k = 0; k < KB; ++k) o[e * NB + 1 + k] = nz ? p[k] * rcp : 0.0f;
    }
    float4* dst = (float4*)(out + (size_t)i0 * NB);
    #pragma unroll
    for (int q = 0; q < EPT * NB / 4; ++q) dst[q] = ((const float4*)o)[q];
    *(float4*)(out + (size_t)NTOT * NB + i0) = make_float4(msk[0], msk[1], msk[2], msk[3]);
}

extern "C" void kernel_launch(void* const* d_in, const int* in_sizes, int n_in,
                              void* d_out, int out_size, void* d_ws, size_t ws_size,
                              hipStream_t stream) {
    const float* expr = (const float*)d_in[0];
    const float* W1   = (const float*)d_in[1];
    const float* b1   = (const float*)d_in[2];
    const float* W2   = (const float*)d_in[3];
    const float* b2   = (const float*)d_in[4];
    float* out = (float*)d_out;
    const int nblocks = NTOT / (BLOCK * EPT);  // 2500

    if (ws_size >= (size_t)WS_BYTES) {
        float* ws = (float*)d_ws;
        setup_kernel<<<65, 64, 0, stream>>>(W1, b1, W2, b2, ws);
        main_kernel<<<nblocks, BLOCK, 0, stream>>>(expr, ws, out);
    } else {
        fused_kernel<<<nblocks, BLOCK, 0, stream>>>(expr, W1, b1, W2, b2, out);
    }
}

// Round 7
// 141.576 us; speedup vs baseline: 1.0291x; 1.0291x over previous
//
#include <hip/hip_runtime.h>
#include <math.h>

#define HID 64
#define KB 9            // NUM_BINS - 1
#define NB 10
#define NTOT (128 * 20000)
#define EPT 2           // elements/thread: 20 floats = 5 f4s -> identity LDS staging
#define BLOCK 256
#define LEAKY 0.01f
#define RSTRIDE 20      // floats per region row (9 A + 9 C + 2 pad) = 5 f4s
#define TAB_FLOATS (128 + 65 * RSTRIDE)   // 128 padded thresholds + 65 regions = 1428
#define WS_BYTES (TAB_FLOATS * 4)
#define SENT 3.0e38f

typedef float v4f __attribute__((ext_vector_type(4)));

// ---------------- setup: 65 blocks x 64 threads, one region per wave ----------------
// ws[0..127]: sorted thresholds t_j = -b1_j/W1_j padded with +SENT;
// ws[128 + r*RSTRIDE + {k, KB+k}]: A[r][k], C[r][k] with logits_k(x) = A*x + C
// on region r = count(t <= x). Units iterate in ORIGINAL order (R2 bug: the
// sort must only affect the threshold array, never the (W1,b1,W2) pairing).
__global__ __launch_bounds__(64) void setup_kernel(
    const float* __restrict__ W1, const float* __restrict__ b1,
    const float* __restrict__ W2, const float* __restrict__ b2,
    float* __restrict__ ws)
{
    __shared__ float t_lds[HID], w_lds[HID], b_lds[HID], tsrt[HID];
    __shared__ float w2_lds[HID * KB];
    __shared__ float red[18 * 65];   // rows padded to 65 -> conflict-free reduce

    const int j = threadIdx.x;       // unit index (original order)
    const int r = blockIdx.x;        // region index 0..64
    const float w = W1[j], b = b1[j];
    const float t = (w != 0.0f) ? (-b / w) : -SENT;  // w==0: constant sign, park at -inf
    t_lds[j] = t; w_lds[j] = w; b_lds[j] = b;
    #pragma unroll
    for (int q = j; q < HID * KB; q += 64) w2_lds[q] = W2[q];
    __syncthreads();

    int rank = 0;                    // rank sort (unique ranks via index tiebreak)
    for (int i = 0; i < HID; ++i) {
        float ti = t_lds[i];
        rank += (ti < t || (ti == t && i < j)) ? 1 : 0;
    }
    tsrt[rank] = t;
    __syncthreads();

    float xm;   // point strictly inside region r
    if (r == 0)        xm = tsrt[0] - 1.0f;
    else if (r == HID) xm = tsrt[HID - 1] + 1.0f;
    else               xm = 0.5f * (tsrt[r - 1] + tsrt[r]);

    const float s = (fmaf(w, xm, b) >= 0.0f) ? 1.0f : LEAKY;
    #pragma unroll
    for (int k = 0; k < KB; ++k) {
        const float w2s = w2_lds[j * KB + k] * s;
        red[(2 * k) * 65 + j]     = w2s * w;   // A contribution
        red[(2 * k + 1) * 65 + j] = w2s * b;   // C contribution
    }
    __syncthreads();

    if (j < 18) {   // threads 0..17 each sum one row of 64 (deterministic order)
        float acc = 0.0f;
        for (int i = 0; i < HID; ++i) acc += red[j * 65 + i];
        const int k = j >> 1;
        if (j & 1) ws[128 + r * RSTRIDE + KB + k] = acc + b2[k];  // C
        else       ws[128 + r * RSTRIDE + k]      = acc;          // A
    }
    if (r == 0) { ws[j] = tsrt[j]; ws[64 + j] = SENT; }
}

// ---------------- main: table lookup + softmax, identity LDS-staged stores ----------------
// EPT=2: thread's 20 output floats = 5 f4s staged at natural stride 5, so the
// staged LDS IS the block tile in linear order (identity readback — R6's bug
// was staging half a thread's data with a full-thread mapping).
// LDS = 0.5 + 5.2 + 20 KB = 25.7 KB -> 6 blocks/CU (24 waves/CU) vs R4's 3.
__global__ __launch_bounds__(BLOCK) void main_kernel(
    const float* __restrict__ expr, const float* __restrict__ ws,
    float* __restrict__ out)
{
    __shared__ float ts[128];
    __shared__ float tab[65 * RSTRIDE];
    __shared__ v4f so[BLOCK * 5];    // stride 5 (odd) -> all 8 bank-quads on writes

    const int tid = threadIdx.x;
    for (int t = tid; t < TAB_FLOATS; t += BLOCK) {
        float v = ws[t];
        if (t < 128) ts[t] = v; else tab[t - 128] = v;
    }
    __syncthreads();

    const int i0 = (blockIdx.x * BLOCK + tid) * EPT;
    const float2 xv = *(const float2*)(expr + i0);
    float x[EPT] = {xv.x, xv.y};
    float o[EPT * NB];
    float msk[EPT];
    #pragma unroll
    for (int e = 0; e < EPT; ++e) {
        const float xe = x[e];
        // region = count(sorted thresholds <= xe); padding keeps all 7 probes in-bounds
        int idx = 0;
        #pragma unroll
        for (int s = 64; s >= 1; s >>= 1)
            idx += (ts[idx + s - 1] <= xe) ? s : 0;
        // whole 20-float row as 5 batched b128 LDS reads (mostly broadcast: 90% zeros)
        const v4f* rowv = (const v4f*)(tab + idx * RSTRIDE);
        v4f r0 = rowv[0], r1 = rowv[1], r2 = rowv[2], r3 = rowv[3], r4 = rowv[4];
        const float A[KB] = {r0.x, r0.y, r0.z, r0.w, r1.x, r1.y, r1.z, r1.w, r2.x};
        const float C[KB] = {r2.y, r2.z, r2.w, r3.x, r3.y, r3.z, r3.w, r4.x, r4.y};
        float lg[KB];
        #pragma unroll
        for (int k = 0; k < KB; ++k) lg[k] = fmaf(A[k], xe, C[k]);
        float m = lg[0];
        #pragma unroll
        for (int k = 1; k < KB; ++k) m = fmaxf(m, lg[k]);
        float p[KB];
        float s = 0.0f;
        #pragma unroll
        for (int k = 0; k < KB; ++k) { p[k] = __expf(lg[k] - m); s += p[k]; }
        const float rcp = __frcp_rn(s);
        const bool nz = (xe != 0.0f);
        msk[e] = nz ? 1.0f : 0.0f;
        o[e * NB] = nz ? 0.0f : 1.0f;
        #pragma unroll
        for (int k = 0; k < KB; ++k) o[e * NB + 1 + k] = nz ? p[k] * rcp : 0.0f;
    }

    // mask output: lane-contiguous float2
    *(float2*)(out + (size_t)NTOT * NB + i0) = make_float2(msk[0], msk[1]);

    // probs: stage thread's 5 f4s; staged layout == block tile linear order.
    #pragma unroll
    for (int q = 0; q < 5; ++q) so[tid * 5 + q] = ((const v4f*)o)[q];
    __syncthreads();
    float* gout = out + (size_t)blockIdx.x * (BLOCK * EPT * NB);
    #pragma unroll
    for (int q = 0; q < 5; ++q) {
        const int g = q * BLOCK + tid;       // linear == physical (identity)
        ((v4f*)gout)[g] = so[g];
    }
}

// ---------------- fallback if d_ws too small: self-contained, per-block table ----------------
__global__ __launch_bounds__(BLOCK) void fused_kernel(
    const float* __restrict__ expr,
    const float* __restrict__ W1, const float* __restrict__ b1,
    const float* __restrict__ W2, const float* __restrict__ b2,
    float* __restrict__ out)
{
    __shared__ float ts[128];
    __shared__ float tab[65 * RSTRIDE];
    __shared__ float st[HID], sw[HID], sb[HID], tsrt[HID];
    const int tid = threadIdx.x;
    if (tid < HID) {
        float w = W1[tid], b = b1[tid];
        st[tid] = (w != 0.0f) ? (-b / w) : -SENT;
        sw[tid] = w; sb[tid] = b;
    }
    __syncthreads();
    if (tid < HID) {
        float t = st[tid];
        int r = 0;
        for (int i = 0; i < HID; ++i) {
            float ti = st[i];
            r += (ti < t || (ti == t && i < tid)) ? 1 : 0;
        }
        tsrt[r] = t;
    }
    __syncthreads();
    if (tid < 128) ts[tid] = (tid < HID) ? tsrt[tid] : SENT;
    for (int item = tid; item < 65 * KB; item += BLOCK) {
        int r = item / KB, k = item - r * KB;
        float xm;
        if (r == 0)        xm = tsrt[0] - 1.0f;
        else if (r == HID) xm = tsrt[HID - 1] + 1.0f;
        else               xm = 0.5f * (tsrt[r - 1] + tsrt[r]);
        float A = 0.0f, C = b2[k];
        for (int j = 0; j < HID; ++j) {
            float w = sw[j], bb = sb[j];
            float s = (fmaf(w, xm, bb) >= 0.0f) ? 1.0f : LEAKY;
            float w2s = W2[j * KB + k] * s;
            A = fmaf(w2s, w, A);
            C = fmaf(w2s, bb, C);
        }
        tab[r * RSTRIDE + k] = A;
        tab[r * RSTRIDE + KB + k] = C;
    }
    __syncthreads();
    const int i0 = (blockIdx.x * BLOCK + tid) * EPT;
    const float2 xv = *(const float2*)(expr + i0);
    float x[EPT] = {xv.x, xv.y};
    float o[EPT * NB]; float msk[EPT];
    #pragma unroll
    for (int e = 0; e < EPT; ++e) {
        const float xe = x[e];
        int idx = 0;
        #pragma unroll
        for (int s = 64; s >= 1; s >>= 1) idx += (ts[idx + s - 1] <= xe) ? s : 0;
        const float* row = tab + idx * RSTRIDE;
        float lg[KB];
        #pragma unroll
        for (int k = 0; k < KB; ++k) lg[k] = fmaf(row[k], xe, row[KB + k]);
        float m = lg[0];
        #pragma unroll
        for (int k = 1; k < KB; ++k) m = fmaxf(m, lg[k]);
        float p[KB]; float s = 0.0f;
        #pragma unroll
        for (int k = 0; k < KB; ++k) { p[k] = __expf(lg[k] - m); s += p[k]; }
        const float rcp = __frcp_rn(s);
        const bool nz = (xe != 0.0f);
        msk[e] = nz ? 1.0f : 0.0f;
        o[e * NB] = nz ? 0.0f : 1.0f;
        #pragma unroll
        for (int k = 0; k < KB; ++k) o[e * NB + 1 + k] = nz ? p[k] * rcp : 0.0f;
    }
    float* dst = out + (size_t)i0 * NB;
    #pragma unroll
    for (int q = 0; q < EPT * NB / 4; ++q) ((float4*)dst)[q] = ((const float4*)o)[q];
    *(float2*)(out + (size_t)NTOT * NB + i0) = make_float2(msk[0], msk[1]);
}

extern "C" void kernel_launch(void* const* d_in, const int* in_sizes, int n_in,
                              void* d_out, int out_size, void* d_ws, size_t ws_size,
                              hipStream_t stream) {
    const float* expr = (const float*)d_in[0];
    const float* W1   = (const float*)d_in[1];
    const float* b1   = (const float*)d_in[2];
    const float* W2   = (const float*)d_in[3];
    const float* b2   = (const float*)d_in[4];
    float* out = (float*)d_out;
    const int nblocks = NTOT / (BLOCK * EPT);  // 5000

    if (ws_size >= (size_t)WS_BYTES) {
        float* ws = (float*)d_ws;
        setup_kernel<<<65, 64, 0, stream>>>(W1, b1, W2, b2, ws);
        main_kernel<<<nblocks, BLOCK, 0, stream>>>(expr, ws, out);
    } else {
        fused_kernel<<<nblocks, BLOCK, 0, stream>>>(expr, W1, b1, W2, b2, out);
    }
}